// Round 15
// baseline (87.023 us; speedup 1.0000x reference)
//
#include <hip/hip_runtime.h>
#include <hip/hip_bf16.h>

// GAT layer, N=4096, FIN=512, H=4 heads, F=64.
// R15: R12 base (best, 70.9) + K01 gemm moved to MFMA. The f32 vector GEMM
// (14 instr / 8 FMA, 2 blocks/CU tail) was the long pole; split-bf16 MFMA
// (hi+lo trunc, 3 terms, ~2^-16 rel err) computes D = Wt*X = XW^T directly
// in the Vhi layout; scores reduce from the accumulator via 2 shfl_xor.
// Gemm (256 blocks x 4waves=heads, 16 nodes each) hides under the 64MB
// A-pack stream (1024 blocks, R12's exact pattern).
//   KW:  wt_split - W[512][256] -> Wt_hi/lo[256][512] bf16 (trunc split)
//   K01: blocks<256 = MFMA gemm+scores+V; blocks>=256 = ballot mask-pack
//   K3:  64 rows/block, 20 MFMA/cc, trunc-packed P, raw v_exp_f32,
//        no max-subtraction (scores bounded -> softmax exact). (R12)
//   K4:  float4 combine, normalize, ELU. (R12)
// ws: pacc njb*4MB | f1h | f2h | Vhi 2MB | plsum | Ab 2MB | Wth | Wtl.

#define NN   4096
#define FIN  512
#define H    4
#define F    64
#define HF   256
#define LOG2E 1.44269504088896340736f

typedef __attribute__((ext_vector_type(4))) float f32x4;
typedef __attribute__((ext_vector_type(8))) short short8;

union U8 { short8 s; unsigned int w[4]; };

// ---------------- KW: W transpose + trunc bf16 split ----------------
// Wt_hi[hf][k] = top16(W[k][hf]); Wt_lo = trunc-bf16(W - hi). 64 blocks.
__global__ __launch_bounds__(256) void wt_split(
        const float* __restrict__ W, unsigned short* __restrict__ Wth,
        unsigned short* __restrict__ Wtl) {
    const int gid = blockIdx.x * 256 + threadIdx.x;   // 0..16383
    const int hf = gid >> 6;
    const int k0 = (gid & 63) * 8;
    unsigned short h8[8], l8[8];
#pragma unroll
    for (int e = 0; e < 8; ++e) {
        float x = W[(size_t)(k0 + e) * HF + hf];
        unsigned u = __float_as_uint(x);
        float lo = x - __uint_as_float(u & 0xFFFF0000u);
        h8[e] = (unsigned short)(u >> 16);
        l8[e] = (unsigned short)(__float_as_uint(lo) >> 16);
    }
    *(short8*)&Wth[(size_t)hf * FIN + k0] = *(const short8*)h8;
    *(short8*)&Wtl[(size_t)hf * FIN + k0] = *(const short8*)l8;
}

// ---------------- K01: MFMA gemm+scores+V | mask-pack ----------------
// grid 1280: blocks 0..255 = gemm (i0 = b*16, wave = head);
//            blocks 256..1279 = pack (R12 pattern).
__global__ __launch_bounds__(256) void gemm_scores_pack(
        const float* __restrict__ X,
        const unsigned short* __restrict__ Wth,
        const unsigned short* __restrict__ Wtl,
        const float* __restrict__ a_src, const float* __restrict__ a_dst,
        const int* __restrict__ A,
        float* __restrict__ f1h, float* __restrict__ f2h,
        unsigned short* __restrict__ Vhi,
        unsigned long long* __restrict__ Ab) {
    if (blockIdx.x >= 256) {
        const int pb   = blockIdx.x - 256;                    // 0..1023
        const int gw   = (pb * 256 + threadIdx.x) >> 6;
        const int lane = threadIdx.x & 63;
        const int nchunk = NN * NN / 64;                      // 262144
        for (int c = gw; c < nchunk; c += 4096) {
            int a = A[(size_t)c * 64 + lane];
            unsigned long long m = __ballot(a != 0);
            if (lane == 0) Ab[c] = m;
        }
        return;
    }

    const int h    = threadIdx.x >> 6;        // wave = head
    const int lane = threadIdx.x & 63;
    const int il = lane & 15;                 // A row (f) / B col (i)
    const int kg = lane >> 4;                 // k-group
    const int i0 = blockIdx.x * 16;

    const float* xrow = X + (size_t)(i0 + il) * FIN + kg * 8;
    const unsigned short* wh = Wth + (size_t)(h * F + il) * FIN + kg * 8;
    const unsigned short* wl = Wtl + (size_t)(h * F + il) * FIN + kg * 8;

    f32x4 acc[4];
#pragma unroll
    for (int ft = 0; ft < 4; ++ft) acc[ft] = (f32x4){0.f, 0.f, 0.f, 0.f};

#pragma unroll 2
    for (int k0 = 0; k0 < FIN; k0 += 32) {
        float4 x0 = *(const float4*)(xrow + k0);
        float4 x1 = *(const float4*)(xrow + k0 + 4);
        float xs[8] = {x0.x, x0.y, x0.z, x0.w, x1.x, x1.y, x1.z, x1.w};
        U8 xh, xl;
#pragma unroll
        for (int e = 0; e < 8; e += 2) {
            unsigned ua = __float_as_uint(xs[e]), ub = __float_as_uint(xs[e + 1]);
            xh.w[e >> 1] = __builtin_amdgcn_perm(ub, ua, 0x07060302u);
            float la = xs[e]     - __uint_as_float(ua & 0xFFFF0000u);
            float lb = xs[e + 1] - __uint_as_float(ub & 0xFFFF0000u);
            xl.w[e >> 1] = __builtin_amdgcn_perm(__float_as_uint(lb),
                                                 __float_as_uint(la), 0x07060302u);
        }
#pragma unroll
        for (int ft = 0; ft < 4; ++ft) {
            short8 ah = *(const short8*)(wh + (size_t)ft * 16 * FIN + k0);
            short8 al = *(const short8*)(wl + (size_t)ft * 16 * FIN + k0);
            acc[ft] = __builtin_amdgcn_mfma_f32_16x16x32_bf16(ah, xh.s, acc[ft], 0, 0, 0);
            acc[ft] = __builtin_amdgcn_mfma_f32_16x16x32_bf16(ah, xl.s, acc[ft], 0, 0, 0);
            acc[ft] = __builtin_amdgcn_mfma_f32_16x16x32_bf16(al, xh.s, acc[ft], 0, 0, 0);
        }
    }

    // D[f, i]: col i = il, row f = ft*16 + kg*4 + r.
    // scores: s = sum_f D[f,i]*a[f]; per-lane partial over (ft, r), then
    // reduce across kg groups (lanes xor 16, 32).
    float s1 = 0.f, s2 = 0.f;
#pragma unroll
    for (int ft = 0; ft < 4; ++ft) {
        float4 a1 = *(const float4*)(a_src + h * F + ft * 16 + kg * 4);
        float4 a2 = *(const float4*)(a_dst + h * F + ft * 16 + kg * 4);
        s1 += acc[ft][0] * a1.x + acc[ft][1] * a1.y
            + acc[ft][2] * a1.z + acc[ft][3] * a1.w;
        s2 += acc[ft][0] * a2.x + acc[ft][1] * a2.y
            + acc[ft][2] * a2.z + acc[ft][3] * a2.w;
    }
    s1 += __shfl_xor(s1, 16, 64); s1 += __shfl_xor(s1, 32, 64);
    s2 += __shfl_xor(s2, 16, 64); s2 += __shfl_xor(s2, 32, 64);
    if (kg == 0) {
        f1h[h * NN + i0 + il] = s1 * LOG2E;
        f2h[h * NN + i0 + il] = s2 * LOG2E;
    }

    // V store: Vhi[hf][n] = RNE-bf16(D[f,i]) — already transposed layout.
#pragma unroll
    for (int ft = 0; ft < 4; ++ft)
#pragma unroll
        for (int r = 0; r < 4; ++r) {
            __hip_bfloat16 b = __float2bfloat16(acc[ft][r]);
            Vhi[(size_t)(h * F + ft * 16 + kg * 4 + r) * NN + i0 + il] =
                __builtin_bit_cast(unsigned short, b);
        }
}

// ---------------- K3: MFMA fused attention (partials) ---------------- (R12)
// grid (64, njb): ib = 64-row block (4 rowtiles), jb = JLEN strip. wave=head.
template <int JLEN>
__global__ __launch_bounds__(256) void gat_attn_mfma(
        const unsigned int* __restrict__ Ab32,
        const unsigned short* __restrict__ Vhi,
        const float* __restrict__ f1h, const float* __restrict__ f2h,
        float* __restrict__ pacc, float* __restrict__ plsum) {
    constexpr int NCC = JLEN / 32;
    const int ib = blockIdx.x, jb = blockIdx.y;
    const int h    = threadIdx.x >> 6;
    const int lane = threadIdx.x & 63;
    const int il = lane & 15;
    const int kg = lane >> 4;
    const int sh = kg * 8;
    const int ibase = ib * 64 + il;

    float c[4];
#pragma unroll
    for (int rt = 0; rt < 4; ++rt) c[rt] = f1h[h * NN + ibase + rt * 16];

    const unsigned int* abp[4];
#pragma unroll
    for (int rt = 0; rt < 4; ++rt)
        abp[rt] = Ab32 + (size_t)(ibase + rt * 16) * (NN / 32) + jb * (JLEN / 32);

    const float* f2b = f2h + (size_t)h * NN + jb * JLEN + sh;

    const unsigned short* vb[4];
#pragma unroll
    for (int ft = 0; ft < 4; ++ft)
        vb[ft] = Vhi + (size_t)(h * F + ft * 16 + il) * NN + jb * JLEN + sh;

    f32x4 acc[4][4], lac[4];
#pragma unroll
    for (int rt = 0; rt < 4; ++rt) {
        lac[rt] = (f32x4){0.f, 0.f, 0.f, 0.f};
#pragma unroll
        for (int ft = 0; ft < 4; ++ft) acc[rt][ft] = (f32x4){0.f, 0.f, 0.f, 0.f};
    }

    short8 ones;
#pragma unroll
    for (int e = 0; e < 8; ++e) ones[e] = (short)0x3F80;   // bf16 1.0

#pragma unroll 2
    for (int cc = 0; cc < NCC; ++cc) {
        unsigned int m[4];
#pragma unroll
        for (int rt = 0; rt < 4; ++rt) m[rt] = abp[rt][cc] >> sh;

        float4 ga = *(const float4*)(f2b + cc * 32);
        float4 gb = *(const float4*)(f2b + cc * 32 + 4);
        float gv[8] = {ga.x, ga.y, ga.z, ga.w, gb.x, gb.y, gb.z, gb.w};

        short8 bh[4];
#pragma unroll
        for (int ft = 0; ft < 4; ++ft)
            bh[ft] = *reinterpret_cast<const short8*>(vb[ft] + cc * 32);

#pragma unroll
        for (int rt = 0; rt < 4; ++rt) {
            float pf[8];
#pragma unroll
            for (int e = 0; e < 8; ++e) {
                float s = c[rt] + gv[e];
                s = fmaxf(s, 0.2f * s);                 // leaky relu
                float q = __builtin_amdgcn_exp2f(s);    // raw v_exp_f32
                pf[e] = ((m[rt] >> e) & 1u) ? q : 0.f;
            }
            U8 pa;
#pragma unroll
            for (int e = 0; e < 8; e += 2)
                pa.w[e >> 1] = __builtin_amdgcn_perm(__float_as_uint(pf[e + 1]),
                                                     __float_as_uint(pf[e]),
                                                     0x07060302u);
#pragma unroll
            for (int ft = 0; ft < 4; ++ft)
                acc[rt][ft] = __builtin_amdgcn_mfma_f32_16x16x32_bf16(
                    pa.s, bh[ft], acc[rt][ft], 0, 0, 0);
            lac[rt] = __builtin_amdgcn_mfma_f32_16x16x32_bf16(
                pa.s, ones, lac[rt], 0, 0, 0);
        }
    }

    float* pb = pacc + (size_t)jb * NN * HF + (size_t)(ib * 64) * HF;
#pragma unroll
    for (int rt = 0; rt < 4; ++rt)
#pragma unroll
        for (int ft = 0; ft < 4; ++ft)
#pragma unroll
            for (int r = 0; r < 4; ++r)
                pb[(rt * 16 + kg * 4 + r) * HF + h * F + ft * 16 + il] = acc[rt][ft][r];

    if (il == 0) {
#pragma unroll
        for (int rt = 0; rt < 4; ++rt)
#pragma unroll
            for (int r = 0; r < 4; ++r)
                plsum[(size_t)jb * NN * H
                      + (size_t)(ib * 64 + rt * 16 + kg * 4 + r) * H + h] = lac[rt][r];
    }
}

// ---------------- K4: combine partials, normalize, ELU (float4) ----------
__global__ __launch_bounds__(256) void finalize(
        const float* __restrict__ pacc, const float* __restrict__ plsum,
        const unsigned short* __restrict__ Vhi, float* __restrict__ out,
        int njb) {
    const int gid4 = blockIdx.x * 256 + threadIdx.x;   // 0 .. NN*HF/4-1
    const int i = gid4 >> 6, q = gid4 & 63;
    const int h = q >> 4;
    float4 a = make_float4(0.f, 0.f, 0.f, 0.f);
    float l = 0.f;
    for (int jb = 0; jb < njb; ++jb) {
        float4 p = *(const float4*)&pacc[(size_t)jb * NN * HF + (size_t)i * HF + q * 4];
        a.x += p.x; a.y += p.y; a.z += p.z; a.w += p.w;
        l += plsum[(size_t)jb * NN * H + (size_t)i * H + h];
    }
    float av[4] = {a.x, a.y, a.z, a.w};
    if (l == 0.f) {   // empty row: reference softmax degenerates to uniform
#pragma unroll
        for (int c = 0; c < 4; ++c) {
            const unsigned short* col = Vhi + (size_t)(q * 4 + c) * NN;
            float s = 0.f;
            for (int j = 0; j < NN; ++j)
                s += __uint_as_float(((unsigned int)col[j]) << 16);
            av[c] = s;
        }
        l = (float)NN;
    }
    const float rl = 1.0f / l;
    float4 o;
    float* op = &o.x;
#pragma unroll
    for (int c = 0; c < 4; ++c) {
        float v = av[c] * rl;
        op[c] = (v > 0.f) ? v : (__builtin_amdgcn_exp2f(v * LOG2E) - 1.f);
    }
    *(float4*)&out[(size_t)i * HF + q * 4] = o;
}

// ---------------- launch ----------------
extern "C" void kernel_launch(void* const* d_in, const int* in_sizes, int n_in,
                              void* d_out, int out_size, void* d_ws, size_t ws_size,
                              hipStream_t stream) {
    const float* X     = (const float*)d_in[0];
    const int*   A     = (const int*)d_in[1];
    const float* W     = (const float*)d_in[2];
    const float* a_src = (const float*)d_in[3];
    const float* a_dst = (const float*)d_in[4];
    float* out = (float*)d_out;

    // fixed: f1h,f2h | Vhi | Ab | Wth,Wtl
    const size_t fixed = (size_t)2 * NN * H * 4 + (size_t)HF * NN * 2
                       + (size_t)NN * NN / 8 + (size_t)2 * HF * FIN * 2;
    auto need = [&](int njb) {
        return (size_t)njb * NN * HF * 4 + (size_t)njb * NN * H * 4 + fixed;
    };
    const int njb = (ws_size >= need(8)) ? 8 : 4;   // deterministic in ws_size

    float* pacc = (float*)d_ws;
    float* f1h  = pacc + (size_t)njb * NN * HF;
    float* f2h  = f1h + (size_t)NN * H;
    unsigned short* Vhi = (unsigned short*)(f2h + (size_t)NN * H);
    float* plsum = (float*)(Vhi + (size_t)HF * NN);
    unsigned long long* Ab = (unsigned long long*)(plsum + (size_t)njb * NN * H);
    unsigned short* Wth = (unsigned short*)(Ab + (size_t)NN * NN / 64);
    unsigned short* Wtl = Wth + (size_t)HF * FIN;

    wt_split<<<64, 256, 0, stream>>>(W, Wth, Wtl);
    gemm_scores_pack<<<1280, 256, 0, stream>>>(X, Wth, Wtl, a_src, a_dst, A,
                                               f1h, f2h, Vhi, Ab);
    if (njb == 8)
        gat_attn_mfma<512><<<dim3(64, 8), 256, 0, stream>>>(
            (const unsigned int*)Ab, Vhi, f1h, f2h, pacc, plsum);
    else
        gat_attn_mfma<1024><<<dim3(64, 4), 256, 0, stream>>>(
            (const unsigned int*)Ab, Vhi, f1h, f2h, pacc, plsum);
    finalize<<<NN * HF / 4 / 256, 256, 0, stream>>>(pacc, plsum, Vhi, out, njb);
}

// Round 16
// 82.451 us; speedup vs baseline: 1.0555x; 1.0555x over previous
//
#include <hip/hip_runtime.h>
#include <hip/hip_bf16.h>

// GAT layer, N=4096, FIN=512, H=4 heads, F=64.
// R16: R12 base (best, 70.9) + K01 gemm block-count fix. R12's gemm is pinned
// at 512 blocks (2/CU tail) by tile size; R15's MFMA rewrite regressed (1
// wave/SIMD serial chain). Fix: 16x64 tile, 2x2 micro (6 instr/4 FMA), 1024
// gemm blocks = 4/CU tail, LDS 12.75KB -> 8 blocks/CU with pack co-resident.
// Same k-accumulation order -> XW bitwise identical to R12.
//   K01: blocks<1024 = GEMM 16x64/2x2 + scores + V-transpose;
//        blocks>=1024 = grid-stride ballot mask-pack (R12 pattern).
//   K3:  64 rows/block, 20 MFMA/cc, trunc-packed P, raw v_exp_f32,
//        no max-subtraction (scores bounded -> softmax exact). (R12)
//   K4:  float4 combine, normalize, ELU. (R12)
// ws: pacc njb*4MB | f1h | f2h | Vhi 2MB | plsum | Ab 2MB. njb: 8 else 4.

#define NN   4096
#define FIN  512
#define H    4
#define F    64
#define HF   256
#define LOG2E 1.44269504088896340736f

typedef __attribute__((ext_vector_type(4))) float f32x4;
typedef __attribute__((ext_vector_type(8))) short short8;

union U8 { short8 s; unsigned int w[4]; };

// ---------------- K01: fused (GEMM+scores+transpose) | mask-pack ----------
// grid 2048: blocks 0..1023 = gemm (bi = b&255, h = b>>8), 1024..2047 = pack.
__global__ __launch_bounds__(256) void gemm_scores_pack(
        const float* __restrict__ X, const float* __restrict__ W,
        const float* __restrict__ a_src, const float* __restrict__ a_dst,
        const int* __restrict__ A,
        float* __restrict__ f1h, float* __restrict__ f2h,
        unsigned short* __restrict__ Vhi,
        unsigned long long* __restrict__ Ab) {
    if (blockIdx.x >= 1024) {
        const int pb   = blockIdx.x - 1024;                   // 0..1023
        const int gw   = (pb * 256 + threadIdx.x) >> 6;
        const int lane = threadIdx.x & 63;
        const int nchunk = NN * NN / 64;                      // 262144
        for (int c = gw; c < nchunk; c += 4096) {
            int a = A[(size_t)c * 64 + lane];
            unsigned long long m = __ballot(a != 0);
            if (lane == 0) Ab[c] = m;
        }
        return;
    }

    __shared__ float Ast[32][18];            // [k][m], 16 rows + pad
    __shared__ float Bs[32][64];             // [k][n]
    __shared__ unsigned short Vt[64][20];    // [f][n], 16 + pad

    const int bi = blockIdx.x & 255, h = blockIdx.x >> 8;
    const int t  = threadIdx.x;
    const int tx = t & 31, ty = t >> 5;      // cols tx*2+{0,1}, rows ty*2+{0,1}

    float acc[2][2];
#pragma unroll
    for (int r = 0; r < 2; ++r)
#pragma unroll
        for (int c = 0; c < 2; ++c) acc[r][c] = 0.f;

    const int xr = t >> 4, xk = (t & 15) * 2;    // X stage: row, 2 k's
    const int bk = t >> 3, bn = (t & 7) * 8;     // W stage: k, 8 n's

    const float* Xp = X + (size_t)(bi * 16 + xr) * FIN + xk;
    const float* Bp = W + (size_t)bk * HF + h * F + bn;

    for (int k0 = 0; k0 < FIN; k0 += 32) {
        float2 xv  = *(const float2*)(Xp + k0);
        float4 bv0 = *(const float4*)(Bp + (size_t)k0 * HF);
        float4 bv1 = *(const float4*)(Bp + (size_t)k0 * HF + 4);
        __syncthreads();
        Ast[xk + 0][xr] = xv.x;
        Ast[xk + 1][xr] = xv.y;
        *(float4*)&Bs[bk][bn] = bv0;
        *(float4*)&Bs[bk][bn + 4] = bv1;
        __syncthreads();
#pragma unroll
        for (int kk = 0; kk < 32; ++kk) {
            float2 a2 = *(const float2*)&Ast[kk][ty * 2];
            float2 b2 = *(const float2*)&Bs[kk][tx * 2];
            acc[0][0] += a2.x * b2.x; acc[0][1] += a2.x * b2.y;
            acc[1][0] += a2.y * b2.x; acc[1][1] += a2.y * b2.y;
        }
    }

    // scores: per-row dot over this thread's 2 cols; reduce across 32 tx
    // lanes (width-32 stays within each wave half).
    float2 as2 = *(const float2*)(a_src + h * F + tx * 2);
    float2 ad2 = *(const float2*)(a_dst + h * F + tx * 2);
#pragma unroll
    for (int r = 0; r < 2; ++r) {
        float s1 = acc[r][0] * as2.x + acc[r][1] * as2.y;
        float s2 = acc[r][0] * ad2.x + acc[r][1] * ad2.y;
#pragma unroll
        for (int off = 1; off < 32; off <<= 1) {
            s1 += __shfl_xor(s1, off, 32);
            s2 += __shfl_xor(s2, off, 32);
        }
        if (tx == 0) {
            const int n = bi * 16 + ty * 2 + r;
            f1h[h * NN + n] = s1 * LOG2E;
            f2h[h * NN + n] = s2 * LOG2E;
        }
    }

    // transposed bf16 V via LDS bounce
    __syncthreads();
#pragma unroll
    for (int r = 0; r < 2; ++r)
#pragma unroll
        for (int c = 0; c < 2; ++c) {
            __hip_bfloat16 b = __float2bfloat16(acc[r][c]);
            Vt[tx * 2 + c][ty * 2 + r] = __builtin_bit_cast(unsigned short, b);
        }
    __syncthreads();
    {
        const int f = t >> 2, ch = t & 3;    // 64 f-rows x 4 chunks of 4 bf16
        unsigned long long v = *(const unsigned long long*)&Vt[f][ch * 4];
        *(unsigned long long*)(Vhi + (size_t)(h * F + f) * NN + bi * 16 + ch * 4) = v;
    }
}

// ---------------- K3: MFMA fused attention (partials) ---------------- (R12)
// grid (64, njb): ib = 64-row block (4 rowtiles), jb = JLEN strip. wave=head.
template <int JLEN>
__global__ __launch_bounds__(256) void gat_attn_mfma(
        const unsigned int* __restrict__ Ab32,
        const unsigned short* __restrict__ Vhi,
        const float* __restrict__ f1h, const float* __restrict__ f2h,
        float* __restrict__ pacc, float* __restrict__ plsum) {
    constexpr int NCC = JLEN / 32;
    const int ib = blockIdx.x, jb = blockIdx.y;
    const int h    = threadIdx.x >> 6;
    const int lane = threadIdx.x & 63;
    const int il = lane & 15;        // MFMA A row / B,C/D col
    const int kg = lane >> 4;        // k-group
    const int sh = kg * 8;
    const int ibase = ib * 64 + il;

    float c[4];
#pragma unroll
    for (int rt = 0; rt < 4; ++rt) c[rt] = f1h[h * NN + ibase + rt * 16];

    const unsigned int* abp[4];
#pragma unroll
    for (int rt = 0; rt < 4; ++rt)
        abp[rt] = Ab32 + (size_t)(ibase + rt * 16) * (NN / 32) + jb * (JLEN / 32);

    const float* f2b = f2h + (size_t)h * NN + jb * JLEN + sh;

    const unsigned short* vb[4];
#pragma unroll
    for (int ft = 0; ft < 4; ++ft)
        vb[ft] = Vhi + (size_t)(h * F + ft * 16 + il) * NN + jb * JLEN + sh;

    f32x4 acc[4][4], lac[4];
#pragma unroll
    for (int rt = 0; rt < 4; ++rt) {
        lac[rt] = (f32x4){0.f, 0.f, 0.f, 0.f};
#pragma unroll
        for (int ft = 0; ft < 4; ++ft) acc[rt][ft] = (f32x4){0.f, 0.f, 0.f, 0.f};
    }

    short8 ones;
#pragma unroll
    for (int e = 0; e < 8; ++e) ones[e] = (short)0x3F80;   // bf16 1.0

#pragma unroll 2
    for (int cc = 0; cc < NCC; ++cc) {
        unsigned int m[4];
#pragma unroll
        for (int rt = 0; rt < 4; ++rt) m[rt] = abp[rt][cc] >> sh;

        float4 ga = *(const float4*)(f2b + cc * 32);
        float4 gb = *(const float4*)(f2b + cc * 32 + 4);
        float gv[8] = {ga.x, ga.y, ga.z, ga.w, gb.x, gb.y, gb.z, gb.w};

        short8 bh[4];
#pragma unroll
        for (int ft = 0; ft < 4; ++ft)
            bh[ft] = *reinterpret_cast<const short8*>(vb[ft] + cc * 32);

#pragma unroll
        for (int rt = 0; rt < 4; ++rt) {
            float pf[8];
#pragma unroll
            for (int e = 0; e < 8; ++e) {
                float s = c[rt] + gv[e];
                s = fmaxf(s, 0.2f * s);                 // leaky relu
                float q = __builtin_amdgcn_exp2f(s);    // raw v_exp_f32
                pf[e] = ((m[rt] >> e) & 1u) ? q : 0.f;
            }
            U8 pa;
#pragma unroll
            for (int e = 0; e < 8; e += 2)
                pa.w[e >> 1] = __builtin_amdgcn_perm(__float_as_uint(pf[e + 1]),
                                                     __float_as_uint(pf[e]),
                                                     0x07060302u);
#pragma unroll
            for (int ft = 0; ft < 4; ++ft)
                acc[rt][ft] = __builtin_amdgcn_mfma_f32_16x16x32_bf16(
                    pa.s, bh[ft], acc[rt][ft], 0, 0, 0);
            lac[rt] = __builtin_amdgcn_mfma_f32_16x16x32_bf16(
                pa.s, ones, lac[rt], 0, 0, 0);
        }
    }

    // C/D layout: col = lane&15, row = (lane>>4)*4 + reg
    float* pb = pacc + (size_t)jb * NN * HF + (size_t)(ib * 64) * HF;
#pragma unroll
    for (int rt = 0; rt < 4; ++rt)
#pragma unroll
        for (int ft = 0; ft < 4; ++ft)
#pragma unroll
            for (int r = 0; r < 4; ++r)
                pb[(rt * 16 + kg * 4 + r) * HF + h * F + ft * 16 + il] = acc[rt][ft][r];

    if (il == 0) {   // ones-MFMA: every col holds the row sum; use col 0
#pragma unroll
        for (int rt = 0; rt < 4; ++rt)
#pragma unroll
            for (int r = 0; r < 4; ++r)
                plsum[(size_t)jb * NN * H
                      + (size_t)(ib * 64 + rt * 16 + kg * 4 + r) * H + h] = lac[rt][r];
    }
}

// ---------------- K4: combine partials, normalize, ELU (float4) ----------
__global__ __launch_bounds__(256) void finalize(
        const float* __restrict__ pacc, const float* __restrict__ plsum,
        const unsigned short* __restrict__ Vhi, float* __restrict__ out,
        int njb) {
    const int gid4 = blockIdx.x * 256 + threadIdx.x;   // 0 .. NN*HF/4-1
    const int i = gid4 >> 6, q = gid4 & 63;
    const int h = q >> 4;
    float4 a = make_float4(0.f, 0.f, 0.f, 0.f);
    float l = 0.f;
    for (int jb = 0; jb < njb; ++jb) {
        float4 p = *(const float4*)&pacc[(size_t)jb * NN * HF + (size_t)i * HF + q * 4];
        a.x += p.x; a.y += p.y; a.z += p.z; a.w += p.w;
        l += plsum[(size_t)jb * NN * H + (size_t)i * H + h];
    }
    float av[4] = {a.x, a.y, a.z, a.w};
    if (l == 0.f) {   // empty row: reference softmax degenerates to uniform
#pragma unroll
        for (int c = 0; c < 4; ++c) {
            const unsigned short* col = Vhi + (size_t)(q * 4 + c) * NN;
            float s = 0.f;
            for (int j = 0; j < NN; ++j)
                s += __uint_as_float(((unsigned int)col[j]) << 16);
            av[c] = s;
        }
        l = (float)NN;
    }
    const float rl = 1.0f / l;
    float4 o;
    float* op = &o.x;
#pragma unroll
    for (int c = 0; c < 4; ++c) {
        float v = av[c] * rl;
        op[c] = (v > 0.f) ? v : (__builtin_amdgcn_exp2f(v * LOG2E) - 1.f);
    }
    *(float4*)&out[(size_t)i * HF + q * 4] = o;
}

// ---------------- launch ----------------
extern "C" void kernel_launch(void* const* d_in, const int* in_sizes, int n_in,
                              void* d_out, int out_size, void* d_ws, size_t ws_size,
                              hipStream_t stream) {
    const float* X     = (const float*)d_in[0];
    const int*   A     = (const int*)d_in[1];
    const float* W     = (const float*)d_in[2];
    const float* a_src = (const float*)d_in[3];
    const float* a_dst = (const float*)d_in[4];
    float* out = (float*)d_out;

    const size_t fixed = (size_t)2 * NN * H * 4 + (size_t)HF * NN * 2
                       + (size_t)NN * NN / 8;
    auto need = [&](int njb) {
        return (size_t)njb * NN * HF * 4 + (size_t)njb * NN * H * 4 + fixed;
    };
    const int njb = (ws_size >= need(8)) ? 8 : 4;   // deterministic in ws_size

    float* pacc = (float*)d_ws;
    float* f1h  = pacc + (size_t)njb * NN * HF;
    float* f2h  = f1h + (size_t)NN * H;
    unsigned short* Vhi = (unsigned short*)(f2h + (size_t)NN * H);
    float* plsum = (float*)(Vhi + (size_t)HF * NN);
    unsigned long long* Ab = (unsigned long long*)(plsum + (size_t)njb * NN * H);

    gemm_scores_pack<<<2048, 256, 0, stream>>>(X, W, a_src, a_dst, A,
                                               f1h, f2h, Vhi, Ab);
    if (njb == 8)
        gat_attn_mfma<512><<<dim3(64, 8), 256, 0, stream>>>(
            (const unsigned int*)Ab, Vhi, f1h, f2h, pacc, plsum);
    else
        gat_attn_mfma<1024><<<dim3(64, 4), 256, 0, stream>>>(
            (const unsigned int*)Ab, Vhi, f1h, f2h, pacc, plsum);
    finalize<<<NN * HF / 4 / 256, 256, 0, stream>>>(pacc, plsum, Vhi, out, njb);
}